// Round 2
// baseline (1066.788 us; speedup 1.0000x reference)
//
#include <hip/hip_runtime.h>
#include <hip/hip_bf16.h>

#define S 8192
#define D 1024
#define QBLK 32
#define NW 8
#define KW 32
#define KVBLK (NW*KW)    // 256
#define NITER (S/KVBLK)  // 32

typedef short short8 __attribute__((ext_vector_type(8)));
typedef float f32x16 __attribute__((ext_vector_type(16)));

__device__ __forceinline__ unsigned short f2bf(float x) {
    unsigned u = __builtin_bit_cast(unsigned, x);
    u += 0x7FFFu + ((u >> 16) & 1u);   // RNE
    return (unsigned short)(u >> 16);
}
__device__ __forceinline__ float fexp2(float x) { return __builtin_amdgcn_exp2f(x); }

// ---- prep: K fp32 -> bf16 (same layout) ----
__global__ void conv_k_kernel(const float* __restrict__ in, unsigned short* __restrict__ out) {
    size_t i = ((size_t)blockIdx.x * 256 + threadIdx.x) * 8;
    const float4* p4 = (const float4*)(in + i);
    float4 a = p4[0], b = p4[1];
    short8 v;
    v[0] = (short)f2bf(a.x); v[1] = (short)f2bf(a.y); v[2] = (short)f2bf(a.z); v[3] = (short)f2bf(a.w);
    v[4] = (short)f2bf(b.x); v[5] = (short)f2bf(b.y); v[6] = (short)f2bf(b.z); v[7] = (short)f2bf(b.w);
    *(short8*)(out + i) = v;
}

// ---- prep: V (S x D fp32) -> V^T (D x S bf16) ----
__global__ void transp_v_kernel(const float* __restrict__ in, unsigned short* __restrict__ out) {
    __shared__ float t[32][33];
    int k0 = blockIdx.x * 32, d0 = blockIdx.y * 32;
    int tx = threadIdx.x, ty = threadIdx.y;
#pragma unroll
    for (int i = 0; i < 4; ++i)
        t[ty + 8 * i][tx] = in[(size_t)(k0 + ty + 8 * i) * D + d0 + tx];
    __syncthreads();
#pragma unroll
    for (int i = 0; i < 4; ++i)
        out[(size_t)(d0 + ty + 8 * i) * S + k0 + tx] = f2bf(t[tx][ty + 8 * i]);
}

// ---- main fused attention ----
template<bool CONV>
__global__ __launch_bounds__(512, 2)
void attn_kernel(const float* __restrict__ Qf,
                 const unsigned short* __restrict__ Kb,
                 const unsigned short* __restrict__ VTb,
                 const float* __restrict__ Kf,
                 const float* __restrict__ Vf,
                 float* __restrict__ Out)
{
    __shared__ unsigned short q_lds[QBLK * D];      // 64KB, swizzled
    __shared__ unsigned short p_lds[QBLK * KVBLK];  // 16KB, swizzled
    __shared__ float red_m[NW][QBLK];
    __shared__ float red_l[NW][QBLK];
    __shared__ float alpha_sh[QBLK];
    __shared__ float invl_sh[QBLK];

    const int tid  = threadIdx.x;
    const int wid  = tid >> 6;
    const int lane = tid & 63;
    const int ln31 = lane & 31;
    const int hi   = (lane >> 5) & 1;
    const int q0   = blockIdx.x * QBLK;
    const int swq  = (ln31 & 7) << 4;

    // ---- stage Q into LDS, scaled by log2(e)/sqrt(D), XOR-swizzled ----
    {
        const float cscale = 1.44269504088896340736f / 32.0f;
        const float* qg = Qf + (size_t)q0 * D;
        char* qb = (char*)q_lds;
#pragma unroll
        for (int it = 0; it < (QBLK * D) / (512 * 8); ++it) {
            int idx = (it * 512 + tid) * 8;
            int qq = idx >> 10, dd = idx & (D - 1);
            const float4* p4 = (const float4*)(qg + idx);
            float4 a = p4[0], b = p4[1];
            short8 v;
            v[0] = (short)f2bf(a.x * cscale); v[1] = (short)f2bf(a.y * cscale);
            v[2] = (short)f2bf(a.z * cscale); v[3] = (short)f2bf(a.w * cscale);
            v[4] = (short)f2bf(b.x * cscale); v[5] = (short)f2bf(b.y * cscale);
            v[6] = (short)f2bf(b.z * cscale); v[7] = (short)f2bf(b.w * cscale);
            int off = qq * 2048 + ((dd * 2) ^ ((qq & 7) << 4));
            *(short8*)(qb + off) = v;
        }
    }

    f32x16 O0, O1, O2, O3;
#pragma unroll
    for (int i = 0; i < 16; ++i) { O0[i] = 0.f; O1[i] = 0.f; O2[i] = 0.f; O3[i] = 0.f; }
    float m_run = -1e30f, l_run = 0.f;

    __syncthreads();

    for (int t = 0; t < NITER; ++t) {
        const int kbase = t * KVBLK;
        const int krow  = kbase + wid * KW + ln31;

        // ---------- scores: S^T = K_w . Q^T (64 MFMA, 2 acc chains) ----------
        f32x16 s0, s1;
#pragma unroll
        for (int i = 0; i < 16; ++i) { s0[i] = 0.f; s1[i] = 0.f; }

        const char* qb = (const char*)q_lds + ln31 * 2048;
        if (CONV) {
            const unsigned short* kg = Kb + (size_t)krow * D + hi * 8;
#pragma unroll 8
            for (int kk = 0; kk < 64; kk += 2) {
                short8 a0 = *(const short8*)(kg + kk * 16);
                short8 b0 = *(const short8*)(qb + (((kk * 16 + hi * 8) * 2) ^ swq));
                s0 = __builtin_amdgcn_mfma_f32_32x32x16_bf16(a0, b0, s0, 0, 0, 0);
                short8 a1 = *(const short8*)(kg + (kk + 1) * 16);
                short8 b1 = *(const short8*)(qb + ((((kk + 1) * 16 + hi * 8) * 2) ^ swq));
                s1 = __builtin_amdgcn_mfma_f32_32x32x16_bf16(a1, b1, s1, 0, 0, 0);
            }
        } else {
            const float* kg = Kf + (size_t)krow * D + hi * 8;
#pragma unroll 4
            for (int kk = 0; kk < 64; kk += 2) {
                const float4* f4 = (const float4*)(kg + kk * 16);
                float4 x = f4[0], y = f4[1];
                short8 a0;
                a0[0] = (short)f2bf(x.x); a0[1] = (short)f2bf(x.y); a0[2] = (short)f2bf(x.z); a0[3] = (short)f2bf(x.w);
                a0[4] = (short)f2bf(y.x); a0[5] = (short)f2bf(y.y); a0[6] = (short)f2bf(y.z); a0[7] = (short)f2bf(y.w);
                short8 b0 = *(const short8*)(qb + (((kk * 16 + hi * 8) * 2) ^ swq));
                s0 = __builtin_amdgcn_mfma_f32_32x32x16_bf16(a0, b0, s0, 0, 0, 0);
                const float4* g4 = (const float4*)(kg + (kk + 1) * 16);
                float4 x1 = g4[0], y1 = g4[1];
                short8 a1;
                a1[0] = (short)f2bf(x1.x); a1[1] = (short)f2bf(x1.y); a1[2] = (short)f2bf(x1.z); a1[3] = (short)f2bf(x1.w);
                a1[4] = (short)f2bf(y1.x); a1[5] = (short)f2bf(y1.y); a1[6] = (short)f2bf(y1.z); a1[7] = (short)f2bf(y1.w);
                short8 b1 = *(const short8*)(qb + ((((kk + 1) * 16 + hi * 8) * 2) ^ swq));
                s1 = __builtin_amdgcn_mfma_f32_32x32x16_bf16(a1, b1, s1, 0, 0, 0);
            }
        }
#pragma unroll
        for (int i = 0; i < 16; ++i) s0[i] += s1[i];

        // ---------- softmax (exp2 domain; scale folded into Q) ----------
        float mloc = s0[0];
#pragma unroll
        for (int r = 1; r < 16; ++r) mloc = fmaxf(mloc, s0[r]);
        mloc = fmaxf(mloc, __shfl_xor(mloc, 32));
        if (lane < 32) red_m[wid][ln31] = mloc;
        __syncthreads();                       // bar A

        float mt = red_m[0][ln31];
#pragma unroll
        for (int w = 1; w < NW; ++w) mt = fmaxf(mt, red_m[w][ln31]);
        float mnew  = fmaxf(m_run, mt);
        float alpha = fexp2(m_run - mnew);

        float pr[16];
        float lloc = 0.f;
#pragma unroll
        for (int r = 0; r < 16; ++r) { pr[r] = fexp2(s0[r] - mnew); lloc += pr[r]; }
        lloc += __shfl_xor(lloc, 32);
        if (lane < 32) { red_l[wid][ln31] = lloc; if (wid == 0) alpha_sh[ln31] = alpha; }

        {   // pack P -> bf16, write swizzled LDS (true k slot = (reg&3)+8*(reg>>2)+4*hi)
            char* pb = (char*)p_lds + ln31 * 512;
#pragma unroll
            for (int g = 0; g < 4; ++g) {
                unsigned p01 = (unsigned)f2bf(pr[4 * g + 0]) | ((unsigned)f2bf(pr[4 * g + 1]) << 16);
                unsigned p23 = (unsigned)f2bf(pr[4 * g + 2]) | ((unsigned)f2bf(pr[4 * g + 3]) << 16);
                uint2 val = make_uint2(p01, p23);
                int koff = (wid * 32 + 8 * g + 4 * hi) * 2;
                *(uint2*)(pb + (koff ^ swq)) = val;
            }
        }
        __syncthreads();                       // bar B

        float lsum = red_l[0][ln31];
#pragma unroll
        for (int w = 1; w < NW; ++w) lsum += red_l[w][ln31];
        l_run = l_run * alpha + lsum;
        m_run = mnew;

        // ---------- rescale O by alpha at this lane's q-patterns ----------
#pragma unroll
        for (int r = 0; r < 16; ++r) {
            float ar = alpha_sh[(r & 3) + 8 * (r >> 2) + 4 * hi];
            O0[r] *= ar; O1[r] *= ar; O2[r] *= ar; O3[r] *= ar;
        }

        // ---------- PV: O += P . V  (64 MFMA, 4 acc chains) ----------
        const char* pbase = (const char*)p_lds + ln31 * 512;
        if (CONV) {
            const unsigned short* vg = VTb + (size_t)(wid * 128 + ln31) * S + kbase + hi * 8;
#pragma unroll 4
            for (int kk = 0; kk < 16; ++kk) {
                short8 pa = *(const short8*)(pbase + ((kk * 32 + hi * 16) ^ swq));
                short8 v0 = *(const short8*)(vg + kk * 16);
                O0 = __builtin_amdgcn_mfma_f32_32x32x16_bf16(pa, v0, O0, 0, 0, 0);
                short8 v1 = *(const short8*)(vg + (size_t)32 * S + kk * 16);
                O1 = __builtin_amdgcn_mfma_f32_32x32x16_bf16(pa, v1, O1, 0, 0, 0);
                short8 v2 = *(const short8*)(vg + (size_t)64 * S + kk * 16);
                O2 = __builtin_amdgcn_mfma_f32_32x32x16_bf16(pa, v2, O2, 0, 0, 0);
                short8 v3 = *(const short8*)(vg + (size_t)96 * S + kk * 16);
                O3 = __builtin_amdgcn_mfma_f32_32x32x16_bf16(pa, v3, O3, 0, 0, 0);
            }
        } else {
            const float* vf = Vf + (size_t)(kbase + hi * 8) * D + wid * 128 + ln31;
#pragma unroll 2
            for (int kk = 0; kk < 16; ++kk) {
                short8 pa = *(const short8*)(pbase + ((kk * 32 + hi * 16) ^ swq));
#pragma unroll
                for (int f = 0; f < 4; ++f) {
                    short8 vb;
#pragma unroll
                    for (int j = 0; j < 8; ++j)
                        vb[j] = (short)f2bf(vf[(size_t)(kk * 16 + j) * D + f * 32]);
                    if (f == 0) O0 = __builtin_amdgcn_mfma_f32_32x32x16_bf16(pa, vb, O0, 0, 0, 0);
                    if (f == 1) O1 = __builtin_amdgcn_mfma_f32_32x32x16_bf16(pa, vb, O1, 0, 0, 0);
                    if (f == 2) O2 = __builtin_amdgcn_mfma_f32_32x32x16_bf16(pa, vb, O2, 0, 0, 0);
                    if (f == 3) O3 = __builtin_amdgcn_mfma_f32_32x32x16_bf16(pa, vb, O3, 0, 0, 0);
                }
            }
        }
        // next iter's p_lds/red writes are fenced by bar A of next iteration
    }

    // ---------- epilogue: O /= l ----------
    if (wid == 0 && lane < 32) invl_sh[ln31] = 1.0f / l_run;
    __syncthreads();

    float* outp = Out + (size_t)q0 * D + wid * 128 + ln31;
#pragma unroll
    for (int r = 0; r < 16; ++r) {
        int qrow = (r & 3) + 8 * (r >> 2) + 4 * hi;
        float inv = invl_sh[qrow];
        outp[(size_t)qrow * D + 0]  = O0[r] * inv;
        outp[(size_t)qrow * D + 32] = O1[r] * inv;
        outp[(size_t)qrow * D + 64] = O2[r] * inv;
        outp[(size_t)qrow * D + 96] = O3[r] * inv;
    }
}

extern "C" void kernel_launch(void* const* d_in, const int* in_sizes, int n_in,
                              void* d_out, int out_size, void* d_ws, size_t ws_size,
                              hipStream_t stream)
{
    const float* q = (const float*)d_in[0];
    const float* k = (const float*)d_in[1];
    const float* v = (const float*)d_in[2];
    float* out = (float*)d_out;

    const size_t need = (size_t)2 * S * D * sizeof(unsigned short);  // 33.6 MB
    if (ws_size >= need) {
        unsigned short* kb = (unsigned short*)d_ws;
        unsigned short* vt = kb + (size_t)S * D;
        hipLaunchKernelGGL(conv_k_kernel, dim3(S * D / (256 * 8)), dim3(256), 0, stream, k, kb);
        hipLaunchKernelGGL(transp_v_kernel, dim3(S / 32, D / 32), dim3(32, 8), 0, stream, v, vt);
        hipLaunchKernelGGL((attn_kernel<true>), dim3(S / QBLK), dim3(512), 0, stream,
                           q, kb, vt, (const float*)nullptr, (const float*)nullptr, out);
    } else {
        hipLaunchKernelGGL((attn_kernel<false>), dim3(S / QBLK), dim3(512), 0, stream,
                           q, (const unsigned short*)nullptr, (const unsigned short*)nullptr, k, v, out);
    }
}